// Round 1
// 1558.322 us; speedup vs baseline: 1.0072x; 1.0072x over previous
//
#include <hip/hip_runtime.h>
#include <hip/hip_bf16.h>

#define N_ROWS 16384
#define DD 128
#define EPSV 1e-5f
#define SLOPE 0.2f
#define KSPLIT 4
#define KCHUNK (N_ROWS / KSPLIT)   // 4096
#define BK 64
#define MT 128

typedef short s16x8 __attribute__((ext_vector_type(8)));
typedef float f32x4 __attribute__((ext_vector_type(4)));

static __device__ inline unsigned short f2bf(float f) {
  union { __hip_bfloat16 h; unsigned short u; } cv;
  cv.h = __float2bfloat16(f);
  return cv.u;
}

static __device__ inline s16x8 pack8(f32x4 lo, f32x4 hi) {
  s16x8 r;
  r[0] = (short)f2bf(lo[0]); r[1] = (short)f2bf(lo[1]);
  r[2] = (short)f2bf(lo[2]); r[3] = (short)f2bf(lo[3]);
  r[4] = (short)f2bf(hi[0]); r[5] = (short)f2bf(hi[1]);
  r[6] = (short)f2bf(hi[2]); r[7] = (short)f2bf(hi[3]);
  return r;
}

// ---------------- Kernel 1: yT[d][i] = sum_k x[i,k] * W[k,d]  (bf16 out) ----
// 16 rows/block (was 8): halves W traffic + loop overhead per output.
// x loads are wave-uniform (rh uniform per wave) -> SMEM; W loads coalesced.
__global__ __launch_bounds__(256) void xw_kernel(const float* __restrict__ x,
                                                 const float* __restrict__ W,
                                                 unsigned short* __restrict__ yT) {
  const int t  = threadIdx.x;
  const int d  = t & 127;
  const int rh = t >> 7;              // 0..1 (wave-uniform)
  const int i0 = blockIdx.x * 16;
  float acc[8] = {0.f, 0.f, 0.f, 0.f, 0.f, 0.f, 0.f, 0.f};
  for (int k = 0; k < DD; ++k) {
    float wv = W[k * DD + d];
#pragma unroll
    for (int rr = 0; rr < 8; ++rr)
      acc[rr] = fmaf(x[(size_t)(i0 + rh + 2 * rr) * DD + k], wv, acc[rr]);
  }
#pragma unroll
  for (int rr = 0; rr < 8; ++rr)
    yT[(size_t)d * N_ROWS + i0 + rh + 2 * rr] = f2bf(acc[rr]);
}

// ---------------- Kernel 2: partial[ks] = A[:, ks-chunk] @ y[ks-chunk, :] ---
// Barrier-free, LDS-free. 512 blocks (128 row-tiles x 4 K-splits), 256 thr =
// 4 waves, each wave owns 32 rows x all 128 cols (A loaded exactly once per
// block). A is loaded fp32 straight into the MFMA A-fragment layout
// (lane: row = l&15, k = (l>>4)*8 + j -- identical indexing to the verified
// LDS version) and converted to bf16 in-register. B (yT, 4 MB total,
// L2/L3-resident) is loaded per-fragment from global. No __syncthreads():
// every wave is an independent load/MFMA stream, so HBM stays saturated
// with no vmcnt(0) barrier drains.
__global__ __launch_bounds__(256, 2) void gemm_kernel(const float* __restrict__ A,
                                                      const unsigned short* __restrict__ yT,
                                                      float* __restrict__ partial) {
  const int t   = threadIdx.x;
  const int bid = blockIdx.x;
  const int ks  = bid >> 7;     // 0..3
  const int rt  = bid & 127;    // row tile
  const int kbase = ks * KCHUNK;
  const int row0  = rt * MT;

  const int lane = t & 63;
  const int wid  = t >> 6;      // 0..3: wave owns rows [row0+wid*32, +32)
  const int mrow = lane & 15;
  const int quad = lane >> 4;   // 0..3
  const int wrow = row0 + wid * 32;

  f32x4 acc[2][8];
#pragma unroll
  for (int i = 0; i < 2; ++i)
#pragma unroll
    for (int j = 0; j < 8; ++j)
      acc[i][j] = (f32x4){0.f, 0.f, 0.f, 0.f};

  const float* A0 = A + (size_t)(wrow + mrow) * N_ROWS + kbase + quad * 8;
  const float* A1 = A0 + (size_t)16 * N_ROWS;                 // mi = 1
  const unsigned short* B0 = yT + (size_t)mrow * N_ROWS + kbase + quad * 8;

  for (int kt = 0; kt < KCHUNK / BK; ++kt) {
#pragma unroll
    for (int ks2 = 0; ks2 < 2; ++ks2) {
      const int ko = kt * BK + ks2 * 32;
      // A: 32B/lane contiguous (2 x dwordx4), fragment-layout direct
      f32x4 a00 = *(const f32x4*)(A0 + ko);
      f32x4 a01 = *(const f32x4*)(A0 + ko + 4);
      f32x4 a10 = *(const f32x4*)(A1 + ko);
      f32x4 a11 = *(const f32x4*)(A1 + ko + 4);
      // B: bf16 fragments straight from global (L2/L3-resident)
      s16x8 bfv[8];
#pragma unroll
      for (int ni = 0; ni < 8; ++ni)
        bfv[ni] = *(const s16x8*)(B0 + (size_t)ni * 16 * N_ROWS + ko);
      s16x8 af0 = pack8(a00, a01);
      s16x8 af1 = pack8(a10, a11);
#pragma unroll
      for (int ni = 0; ni < 8; ++ni) {
        acc[0][ni] = __builtin_amdgcn_mfma_f32_16x16x32_bf16(af0, bfv[ni],
                                                             acc[0][ni], 0, 0, 0);
        acc[1][ni] = __builtin_amdgcn_mfma_f32_16x16x32_bf16(af1, bfv[ni],
                                                             acc[1][ni], 0, 0, 0);
      }
    }
  }

  // epilogue: C/D layout col=lane&15, row=quad*4+reg  [m89-verified]
  float* pout = partial + (size_t)ks * N_ROWS * DD;
#pragma unroll
  for (int mi = 0; mi < 2; ++mi)
#pragma unroll
    for (int ni = 0; ni < 8; ++ni)
#pragma unroll
      for (int r = 0; r < 4; ++r) {
        const int gr = wrow + mi * 16 + quad * 4 + r;
        const int gc = ni * 16 + mrow;
        pout[(size_t)gr * DD + gc] = acc[mi][ni][r];
      }
}

// ---------------- Kernel 3: Hsum = sum partials; column sum/sumsq ----------
__global__ __launch_bounds__(256) void sum_stats_kernel(const float* __restrict__ partial,
                                                        float* __restrict__ hsum,
                                                        float* __restrict__ stats) {
  __shared__ float s1[256], s2[256];
  const int t = threadIdx.x;
  const size_t base = (size_t)blockIdx.x * 8192;
  const float* p0 = partial;
  const float* p1 = partial + (size_t)N_ROWS * DD;
  const float* p2 = partial + 2 * (size_t)N_ROWS * DD;
  const float* p3 = partial + 3 * (size_t)N_ROWS * DD;
  float ls = 0.f, lq = 0.f;
#pragma unroll 4
  for (int i = 0; i < 32; ++i) {
    size_t e = base + t + 256 * (size_t)i;
    float v = p0[e] + p1[e] + p2[e] + p3[e];
    hsum[e] = v;
    ls += v;
    lq += v * v;
  }
  s1[t] = ls; s2[t] = lq;
  __syncthreads();
  if (t < 128) {  // col = t (256 = 2*128, partner t+128 has same column)
    atomicAdd(&stats[t], s1[t] + s1[t + 128]);
    atomicAdd(&stats[128 + t], s2[t] + s2[t + 128]);
  }
}

// ---------------- Kernel 3b: per-column scale/shift (b cancels under BN) ---
__global__ void finalize_stats_kernel(float* __restrict__ stats,
                                      const float* __restrict__ gamma,
                                      const float* __restrict__ beta) {
  int t = threadIdx.x;  // 0..127
  float mean = stats[t] * (1.0f / (float)N_ROWS);
  float var  = stats[128 + t] * (1.0f / (float)N_ROWS) - mean * mean;
  var = fmaxf(var, 0.f);
  float inv = rsqrtf(var + EPSV);
  float sc = gamma[t] * inv;
  stats[256 + t] = sc;
  stats[384 + t] = beta[t] - mean * sc;
}

// ---------------- Kernel 4: affine + LeakyReLU in place --------------------
__global__ __launch_bounds__(256) void norm_kernel(float* __restrict__ out,
                                                   const float* __restrict__ stats) {
  size_t e = (size_t)blockIdx.x * 256 + threadIdx.x;
  int col = (int)(e & 127);
  float v = out[e] * stats[256 + col] + stats[384 + col];
  out[e] = v >= 0.f ? v : SLOPE * v;
}

extern "C" void kernel_launch(void* const* d_in, const int* in_sizes, int n_in,
                              void* d_out, int out_size, void* d_ws, size_t ws_size,
                              hipStream_t stream) {
  const float* x     = (const float*)d_in[0];
  const float* A     = (const float*)d_in[1];
  const float* W     = (const float*)d_in[2];
  // d_in[3] = b : cancels exactly under BatchNorm mean subtraction
  const float* gamma = (const float*)d_in[4];
  const float* beta  = (const float*)d_in[5];
  float* out = (float*)d_out;

  char* ws = (char*)d_ws;
  unsigned short* yT = (unsigned short*)ws;                        // 4 MB
  float* partial = (float*)(ws + (size_t)4 * 1024 * 1024);         // 32 MB
  float* stats   = (float*)(ws + (size_t)36 * 1024 * 1024);        // 2 KB

  hipMemsetAsync(stats, 0, 512 * sizeof(float), stream);
  xw_kernel<<<N_ROWS / 16, 256, 0, stream>>>(x, W, yT);
  gemm_kernel<<<512, 256, 0, stream>>>(A, yT, partial);
  sum_stats_kernel<<<256, 256, 0, stream>>>(partial, out, stats);
  finalize_stats_kernel<<<1, 128, 0, stream>>>(stats, gamma, beta);
  norm_kernel<<<(N_ROWS * DD) / 256, 256, 0, stream>>>(out, stats);
}